// Round 3
// baseline (10711.788 us; speedup 1.0000x reference)
//
#include <hip/hip_runtime.h>

// LSTM: B=64, T=512, I=256, H=512, L=2, O=128. fp32 in/out, bf16 MFMA compute.
//
// v2: persistent cooperative kernel. 64 blocks x 256 threads, resident for the
// whole T=512 sequence; one grid barrier per step (atomic counter in ws).
// Block = (layer = blk>>5, n = blk&31) owns h-cols [n*16, n*16+16) = 64 packed
// gate rows. Weights are preloaded ONCE into VGPRs as 32x32x16 MFMA B-frags
// (wave = N-quadrant x K-half: L0 24 frags/wave, L1 32 frags/wave).
// Per step only activations stream from cache; c-state stays in registers.
// h planes double-buffered in ws (same parities as the verified v1).
//
// ws layout (bytes):
//   0         x_bf16   [64][512][256] bf16   16,777,216
//   16777216  Wpack0   [2048][768]   bf16     3,145,728
//   19922944  Wpack1   [2048][1024]  bf16     4,194,304
//   24117248  h0 planes[2][64][512]  bf16       131,072
//   24248320  h1 planes[2][64][512]  bf16       131,072
//   24379392  barrier counter (u32, zeroed per launch; rest spare, zeroed)

#define B_  64
#define T_  512
#define I0_ 256
#define H_  512
#define BH_ (B_ * H_)

typedef unsigned short ushort_t;
typedef __attribute__((ext_vector_type(8)))  short short8;   // 8 bf16 = 4 VGPR
typedef __attribute__((ext_vector_type(16))) float f32x16;   // 32x32 MFMA C/D

__device__ __forceinline__ unsigned short f2bf(float f) {
    unsigned int u = __builtin_bit_cast(unsigned int, f);
    u += 0x7fffu + ((u >> 16) & 1u);           // RTNE
    return (unsigned short)(u >> 16);
}

// ---- prologue: x fp32 -> bf16 -------------------------------------------
__global__ void conv_x(const float* __restrict__ x, ushort_t* __restrict__ xb) {
    size_t i = ((size_t)blockIdx.x * 256 + threadIdx.x) * 4;
    float4 v = *(const float4*)(x + i);
    ushort4 o;
    o.x = f2bf(v.x); o.y = f2bf(v.y); o.z = f2bf(v.z); o.w = f2bf(v.w);
    *(ushort4*)(xb + i) = o;
}

// ---- prologue: pack [W_ih | W_hh] -> bf16, rows grouped per col-group ----
// packed row p = n*64 + strip*16 + jj  ->  gate row g = strip*512 + n*16 + jj
__global__ void pack_w(const float* __restrict__ wih0, const float* __restrict__ whh0,
                       const float* __restrict__ wih1, const float* __restrict__ whh1,
                       ushort_t* __restrict__ wp0, ushort_t* __restrict__ wp1) {
    int p = blockIdx.x;
    int layer = p >> 11;
    int row = p & 2047;
    int n = row >> 6, rem = row & 63;
    int st = rem >> 4, jj = rem & 15;
    int g = st * 512 + n * 16 + jj;
    if (layer == 0) {
        for (int k = threadIdx.x; k < 768; k += 256) {
            float v = (k < 256) ? wih0[(size_t)g * 256 + k]
                                : whh0[(size_t)g * 512 + (k - 256)];
            wp0[(size_t)row * 768 + k] = f2bf(v);
        }
    } else {
        for (int k = threadIdx.x; k < 1024; k += 256) {
            float v = (k < 512) ? wih1[(size_t)g * 512 + k]
                                : whh1[(size_t)g * 512 + (k - 512)];
            wp1[(size_t)row * 1024 + k] = f2bf(v);
        }
    }
}

// ---- prologue: zero h planes + barrier counter area ----------------------
__global__ void zero_ws(uint4* p) {
    p[(size_t)blockIdx.x * 256 + threadIdx.x] = uint4{0, 0, 0, 0};
}

// ---- grid barrier: monotonic counter, agent-scope ------------------------
__device__ __forceinline__ void gbar(unsigned* cnt, unsigned target) {
    __threadfence();                               // release: flush h writes
    __syncthreads();
    if (threadIdx.x == 0) {
        __hip_atomic_fetch_add(cnt, 1u, __ATOMIC_RELEASE, __HIP_MEMORY_SCOPE_AGENT);
        while (__hip_atomic_load(cnt, __ATOMIC_RELAXED, __HIP_MEMORY_SCOPE_AGENT) < target) { }
    }
    __syncthreads();
    __threadfence();                               // acquire: invalidate L1/L2
}

// ---- persistent kernel ---------------------------------------------------
// global step s in [0,512]. layer0 computes t=s (s<512); layer1 t=s-1 (s>=1).
// h0: layer0 reads plane (s+1)&1, writes plane s&1.
// h1: layer1 reads plane s&1, writes plane (s+1)&1; input = h0 plane (s+1)&1.
__global__ __launch_bounds__(256, 1) void lstm_persist(
    const ushort_t* __restrict__ xbf,
    const ushort_t* __restrict__ wp0,
    const ushort_t* __restrict__ wp1,
    ushort_t* __restrict__ h0,
    ushort_t* __restrict__ h1,
    const float* __restrict__ bi0, const float* __restrict__ bh0,
    const float* __restrict__ bi1, const float* __restrict__ bh1,
    float* __restrict__ dout,
    unsigned* __restrict__ barcnt)
{
    __shared__ float xch[2][64][68];   // [K-half][batch][gate-row], pad 68 -> conflict-free

    const int blk   = blockIdx.x;
    const int layer = blk >> 5;
    const int n     = blk & 31;
    const int tid   = threadIdx.x;
    const int lane  = tid & 63;
    const int wv    = tid >> 6;     // wave 0..3
    const int nq    = wv & 1;       // gate-row quadrant (32 rows)
    const int kq    = wv >> 1;      // K-half
    const int c31   = lane & 31;
    const int hi    = lane >> 5;
    const int k8    = hi * 8;       // A/B fragment k sub-offset

    // elementwise mapping: thread -> (4 batches, 1 col)
    const int j   = tid & 15;
    const int bq  = tid >> 4;
    const int col = n * 16 + j;

    const float* bi = layer ? bi1 : bi0;
    const float* bh = layer ? bh1 : bh0;
    const float bI = bi[col]        + bh[col];
    const float bF = bi[512 + col]  + bh[512 + col];
    const float bG = bi[1024 + col] + bh[1024 + col];
    const float bO = bi[1536 + col] + bh[1536 + col];

    float cr[4] = {0.f, 0.f, 0.f, 0.f};   // c-state lives in registers all T steps

    if (layer == 0) {
        // B-frags: packed rows n*64 + nq*32 + c31, K-half kq (384 wide), 24 frags
        short8 wf[24];
        {
            const ushort_t* wb = wp0 + ((size_t)(n * 64 + nq * 32 + c31)) * 768 + kq * 384 + k8;
            #pragma unroll
            for (int kc = 0; kc < 24; ++kc) wf[kc] = *(const short8*)(wb + kc * 16);
        }
        for (int s = 0; s < 512; ++s) {
            const int rp = (s + 1) & 1;
            const int wq = s & 1;
            f32x16 acc0 = {0.f,0.f,0.f,0.f,0.f,0.f,0.f,0.f,0.f,0.f,0.f,0.f,0.f,0.f,0.f,0.f};
            f32x16 acc1 = {0.f,0.f,0.f,0.f,0.f,0.f,0.f,0.f,0.f,0.f,0.f,0.f,0.f,0.f,0.f,0.f};
            const ushort_t* hr = h0 + rp * BH_;
            if (kq == 0) {
                // K 0..383: x[t] (k<256) then h[0..128)
                const ushort_t* ax0 = xbf + (size_t)(c31)      * (T_ * I0_) + (size_t)s * I0_ + k8;
                const ushort_t* ax1 = xbf + (size_t)(32 + c31) * (T_ * I0_) + (size_t)s * I0_ + k8;
                const ushort_t* ah0 = hr + (c31)      * H_ + k8;
                const ushort_t* ah1 = hr + (32 + c31) * H_ + k8;
                #pragma unroll
                for (int kc = 0; kc < 24; ++kc) {
                    short8 a0v, a1v;
                    if (kc < 16) {
                        a0v = *(const short8*)(ax0 + kc * 16);
                        a1v = *(const short8*)(ax1 + kc * 16);
                    } else {
                        a0v = *(const short8*)(ah0 + (kc - 16) * 16);
                        a1v = *(const short8*)(ah1 + (kc - 16) * 16);
                    }
                    acc0 = __builtin_amdgcn_mfma_f32_32x32x16_bf16(a0v, wf[kc], acc0, 0, 0, 0);
                    acc1 = __builtin_amdgcn_mfma_f32_32x32x16_bf16(a1v, wf[kc], acc1, 0, 0, 0);
                }
            } else {
                // K 384..767: h[128..512)
                const ushort_t* ah0 = hr + (c31)      * H_ + 128 + k8;
                const ushort_t* ah1 = hr + (32 + c31) * H_ + 128 + k8;
                #pragma unroll
                for (int kc = 0; kc < 24; ++kc) {
                    short8 a0v = *(const short8*)(ah0 + kc * 16);
                    short8 a1v = *(const short8*)(ah1 + kc * 16);
                    acc0 = __builtin_amdgcn_mfma_f32_32x32x16_bf16(a0v, wf[kc], acc0, 0, 0, 0);
                    acc1 = __builtin_amdgcn_mfma_f32_32x32x16_bf16(a1v, wf[kc], acc1, 0, 0, 0);
                }
            }
            // D layout (32x32): col = lane&31 (gate row), row = (r&3)+8*(r>>2)+4*hi (batch)
            #pragma unroll
            for (int r = 0; r < 16; ++r) {
                int brow = (r & 3) + 8 * (r >> 2) + 4 * hi;
                xch[kq][brow][nq * 32 + c31]      = acc0[r];
                xch[kq][32 + brow][nq * 32 + c31] = acc1[r];
            }
            __syncthreads();
            ushort_t* hw = h0 + wq * BH_;
            #pragma unroll
            for (int r = 0; r < 4; ++r) {
                const int bb = bq * 4 + r;
                float iv = xch[0][bb][j]      + xch[1][bb][j]      + bI;
                float fv = xch[0][bb][16 + j] + xch[1][bb][16 + j] + bF;
                float gv = xch[0][bb][32 + j] + xch[1][bb][32 + j] + bG;
                float ov = xch[0][bb][48 + j] + xch[1][bb][48 + j] + bO;
                float ig = 1.f / (1.f + __expf(-iv));
                float fg = 1.f / (1.f + __expf(-fv));
                float og = 1.f / (1.f + __expf(-ov));
                float cn = fg * cr[r] + ig * tanhf(gv);
                cr[r] = cn;
                float hn = og * tanhf(cn);
                hw[bb * H_ + col] = f2bf(hn);
                if (s == 511) {
                    dout[16785408 + bb * H_ + col] = hn;   // hidden[0]
                    dout[16850944 + bb * H_ + col] = cn;   // cell[0]
                }
            }
            gbar(barcnt, 64u * (unsigned)(s + 1));
        }
    } else {
        // layer 1: B-frags 32/wave; kq=0 reads h_seq0[t], kq=1 reads h1[t-1]
        short8 wf[32];
        {
            const ushort_t* wb = wp1 + ((size_t)(n * 64 + nq * 32 + c31)) * 1024 + kq * 512 + k8;
            #pragma unroll
            for (int kc = 0; kc < 32; ++kc) wf[kc] = *(const short8*)(wb + kc * 16);
        }
        gbar(barcnt, 64u);                          // s = 0 (idle step)
        for (int s = 1; s <= 512; ++s) {
            const int t  = s - 1;
            const int rp = (s + 1) & 1;
            f32x16 acc0 = {0.f,0.f,0.f,0.f,0.f,0.f,0.f,0.f,0.f,0.f,0.f,0.f,0.f,0.f,0.f,0.f};
            f32x16 acc1 = {0.f,0.f,0.f,0.f,0.f,0.f,0.f,0.f,0.f,0.f,0.f,0.f,0.f,0.f,0.f,0.f};
            const ushort_t* ab = (kq == 0) ? (h0 + rp * BH_)        // h_seq0[t]
                                           : (h1 + (s & 1) * BH_);  // h1[t-1]
            const ushort_t* a0p = ab + (c31)      * H_ + k8;
            const ushort_t* a1p = ab + (32 + c31) * H_ + k8;
            #pragma unroll
            for (int kc = 0; kc < 32; ++kc) {
                short8 a0v = *(const short8*)(a0p + kc * 16);
                short8 a1v = *(const short8*)(a1p + kc * 16);
                acc0 = __builtin_amdgcn_mfma_f32_32x32x16_bf16(a0v, wf[kc], acc0, 0, 0, 0);
                acc1 = __builtin_amdgcn_mfma_f32_32x32x16_bf16(a1v, wf[kc], acc1, 0, 0, 0);
            }
            #pragma unroll
            for (int r = 0; r < 16; ++r) {
                int brow = (r & 3) + 8 * (r >> 2) + 4 * hi;
                xch[kq][brow][nq * 32 + c31]      = acc0[r];
                xch[kq][32 + brow][nq * 32 + c31] = acc1[r];
            }
            __syncthreads();
            ushort_t* hw = h1 + rp * BH_;
            #pragma unroll
            for (int r = 0; r < 4; ++r) {
                const int bb = bq * 4 + r;
                float iv = xch[0][bb][j]      + xch[1][bb][j]      + bI;
                float fv = xch[0][bb][16 + j] + xch[1][bb][16 + j] + bF;
                float gv = xch[0][bb][32 + j] + xch[1][bb][32 + j] + bG;
                float ov = xch[0][bb][48 + j] + xch[1][bb][48 + j] + bO;
                float ig = 1.f / (1.f + __expf(-iv));
                float fg = 1.f / (1.f + __expf(-fv));
                float og = 1.f / (1.f + __expf(-ov));
                float cn = fg * cr[r] + ig * tanhf(gv);
                cr[r] = cn;
                float hn = og * tanhf(cn);
                hw[bb * H_ + col] = f2bf(hn);
                dout[8192 + ((size_t)bb * T_ + t) * H_ + col] = hn;     // lstm_out
                if (t == 511) {
                    dout[16785408 + BH_ + bb * H_ + col] = hn;          // hidden[1]
                    dout[16850944 + BH_ + bb * H_ + col] = cn;          // cell[1]
                }
            }
            if (s < 512) gbar(barcnt, 64u * (unsigned)(s + 1));
        }
    }
}

// ---- final projection: out = h1T @ W_out^T + b_out -----------------------
__global__ void out_gemm(const float* __restrict__ h1T, const float* __restrict__ wout,
                         const float* __restrict__ bout, float* __restrict__ out) {
    int b = blockIdx.x, o = threadIdx.x;
    const float* hr = h1T + (size_t)b * 512;
    const float* wr = wout + (size_t)o * 512;
    float acc = bout[o];
    #pragma unroll 8
    for (int k = 0; k < 512; ++k) acc += hr[k] * wr[k];
    out[b * 128 + o] = acc;
}

extern "C" void kernel_launch(void* const* d_in, const int* in_sizes, int n_in,
                              void* d_out, int out_size, void* d_ws, size_t ws_size,
                              hipStream_t stream)
{
    const float* x    = (const float*)d_in[0];
    const float* wih0 = (const float*)d_in[1];
    const float* whh0 = (const float*)d_in[2];
    const float* bih0 = (const float*)d_in[3];
    const float* bhh0 = (const float*)d_in[4];
    const float* wih1 = (const float*)d_in[5];
    const float* whh1 = (const float*)d_in[6];
    const float* bih1 = (const float*)d_in[7];
    const float* bhh1 = (const float*)d_in[8];
    const float* wout = (const float*)d_in[9];
    const float* bout = (const float*)d_in[10];
    float* out = (float*)d_out;

    char* ws = (char*)d_ws;
    ushort_t* xbf = (ushort_t*)(ws);
    ushort_t* wp0 = (ushort_t*)(ws + 16777216);
    ushort_t* wp1 = (ushort_t*)(ws + 19922944);
    ushort_t* h0  = (ushort_t*)(ws + 24117248);
    ushort_t* h1  = (ushort_t*)(ws + 24248320);
    unsigned* bar = (unsigned*)(ws + 24379392);

    conv_x<<<8192, 256, 0, stream>>>(x, xbf);
    pack_w<<<4096, 256, 0, stream>>>(wih0, whh0, wih1, whh1, wp0, wp1);
    zero_ws<<<128, 256, 0, stream>>>((uint4*)(ws + 24117248));  // h planes + barrier cnt

    void* kargs[] = { (void*)&xbf, (void*)&wp0, (void*)&wp1, (void*)&h0, (void*)&h1,
                      (void*)&bih0, (void*)&bhh0, (void*)&bih1, (void*)&bhh1,
                      (void*)&out, (void*)&bar };
    hipError_t ce = hipLaunchCooperativeKernel((const void*)lstm_persist,
                                               dim3(64), dim3(256), kargs, 0u, stream);
    if (ce != hipSuccess) {
        // fallback: plain launch (64 blocks on 256 CUs — co-resident in practice)
        lstm_persist<<<64, 256, 0, stream>>>(xbf, wp0, wp1, h0, h1,
                                             bih0, bhh0, bih1, bhh1, out, bar);
    }

    // hidden[1] = h1T lives at float offset 16785408 + 64*512
    out_gemm<<<64, 128, 0, stream>>>(out + 16785408 + BH_, wout, bout, out);
}